// Round 1
// baseline (252.773 us; speedup 1.0000x reference)
//
#include <hip/hip_runtime.h>

namespace {

constexpr int B = 2, S = 1024, D = 1024, H = 16, DH = 64;
constexpr int M = B * S;  // 2048 rows
constexpr float EPS = 1e-5f;

using bf16x8 = __attribute__((ext_vector_type(8))) short;  // MFMA A/B frag, K=32 (4 VGPRs)
using bf16x4 = __attribute__((ext_vector_type(4))) short;  // MFMA A/B frag, K=16 (2 VGPRs)
using f32x4  = __attribute__((ext_vector_type(4))) float;  // MFMA C/D frag

typedef const __attribute__((address_space(1))) void* gptr_t;
typedef __attribute__((address_space(3))) void* lptr_t;

__device__ __forceinline__ unsigned short f2bf(float f) {
    union { float f; unsigned u; } v{f};
    unsigned r = v.u + 0x7fffu + ((v.u >> 16) & 1u);  // RNE
    return (unsigned short)(r >> 16);
}

__device__ __forceinline__ float bflo(unsigned u) {
    union { unsigned u; float f; } v{u << 16}; return v.f;
}
__device__ __forceinline__ float bfhi(unsigned u) {
    union { unsigned u; float f; } v{u & 0xffff0000u}; return v.f;
}

__device__ __forceinline__ float wave_sum(float v) {
#pragma unroll
    for (int off = 32; off > 0; off >>= 1) v += __shfl_down(v, off, 64);
    return v;
}

// ---------------- Kernel 0: W fp32 -> bf16 ----------------
__global__ __launch_bounds__(256) void cvt_w_kernel(
    const float* __restrict__ Wq, const float* __restrict__ Wk,
    const float* __restrict__ Wv, unsigned short* __restrict__ Wb)
{
    const float* src = (blockIdx.z == 0) ? Wq : (blockIdx.z == 1) ? Wk : Wv;
    const size_t i = ((size_t)blockIdx.x * 256 + threadIdx.x) * 4;
    float4 f = *reinterpret_cast<const float4*>(src + i);
    ushort4 h;
    h.x = f2bf(f.x); h.y = f2bf(f.y); h.z = f2bf(f.z); h.w = f2bf(f.w);
    *reinterpret_cast<ushort4*>(Wb + (size_t)blockIdx.z * D * D + i) = h;
}

// ---------------- Kernel 1: LN(id) -> id_ln (fp32 + bf16) ----------------
__global__ __launch_bounds__(256) void ln0_kernel(
    const float* __restrict__ x, const float* __restrict__ g,
    const float* __restrict__ bt, float* __restrict__ y,
    unsigned short* __restrict__ yb)
{
    __shared__ float sm[8];
    __shared__ float stats[2];
    const int row = blockIdx.x;
    const int t = threadIdx.x;
    const float4 v = reinterpret_cast<const float4*>(x + (size_t)row * D)[t];
    float s  = v.x + v.y + v.z + v.w;
    float ss = v.x*v.x + v.y*v.y + v.z*v.z + v.w*v.w;
    s = wave_sum(s); ss = wave_sum(ss);
    const int lane = t & 63, wid = t >> 6;
    if (lane == 0) { sm[wid] = s; sm[4 + wid] = ss; }
    __syncthreads();
    if (t == 0) {
        float S1 = sm[0] + sm[1] + sm[2] + sm[3];
        float S2 = sm[4] + sm[5] + sm[6] + sm[7];
        float m  = S1 * (1.0f / D);
        float var = S2 * (1.0f / D) - m * m;
        stats[0] = m; stats[1] = rsqrtf(var + EPS);
    }
    __syncthreads();
    const float m = stats[0], r = stats[1];
    const float4 gv = reinterpret_cast<const float4*>(g)[t];
    const float4 bv = reinterpret_cast<const float4*>(bt)[t];
    float4 o;
    o.x = (v.x - m) * r * gv.x + bv.x;
    o.y = (v.y - m) * r * gv.y + bv.y;
    o.z = (v.z - m) * r * gv.z + bv.z;
    o.w = (v.w - m) * r * gv.w + bv.w;
    reinterpret_cast<float4*>(y + (size_t)row * D)[t] = o;
    ushort4 h; h.x = f2bf(o.x); h.y = f2bf(o.y); h.z = f2bf(o.z); h.w = f2bf(o.w);
    *reinterpret_cast<ushort4*>(yb + (size_t)row * D + t * 4) = h;
}

// ---------------- Kernel 2: q/k/v = id_ln @ W^T, bf16 MFMA 128x128 ----------
// z=0 -> q bf16 [M][D]; z=1 -> k bf16 [M][D]; z=2 -> vT bf16 [B][D][S]
__global__ __launch_bounds__(256) void qkv_mfma_kernel(
    const unsigned short* __restrict__ idln, const unsigned short* __restrict__ Wb,
    unsigned short* __restrict__ q, unsigned short* __restrict__ k,
    unsigned short* __restrict__ vT)
{
    __shared__ unsigned short As[128 * 32];
    __shared__ unsigned short Bs[128 * 32];
    const int zi = blockIdx.z;
    const unsigned short* Bmat = Wb + (size_t)zi * D * D;
    const int m0 = blockIdx.y * 128, n0 = blockIdx.x * 128;
    const int t = threadIdx.x;
    const int w = t >> 6, lane = t & 63;
    const int wm = (w >> 1) * 64, wn = (w & 1) * 64;
    const int quad = lane >> 4, l16 = lane & 15;
    const int srow = t >> 2;          // 0..63
    const int scol = (t & 3) * 8;     // 0,8,16,24 (bf16 elems)

    f32x4 acc[4][4];
#pragma unroll
    for (int i = 0; i < 4; ++i)
#pragma unroll
        for (int j = 0; j < 4; ++j) acc[i][j] = (f32x4){0.f, 0.f, 0.f, 0.f};

    for (int k0 = 0; k0 < D; k0 += 32) {
        __syncthreads();
#pragma unroll
        for (int c = 0; c < 2; ++c) {
            const unsigned short* ga = idln + (size_t)(m0 + srow + c * 64) * D + k0 + scol;
            __builtin_amdgcn_global_load_lds((gptr_t)ga, (lptr_t)(As + t * 8 + c * 2048), 16, 0, 0);
            const unsigned short* gb = Bmat + (size_t)(n0 + srow + c * 64) * D + k0 + scol;
            __builtin_amdgcn_global_load_lds((gptr_t)gb, (lptr_t)(Bs + t * 8 + c * 2048), 16, 0, 0);
        }
        __syncthreads();
        bf16x8 af[4], bfr[4];
#pragma unroll
        for (int i = 0; i < 4; ++i)
            af[i] = *reinterpret_cast<const bf16x8*>(As + (wm + i * 16 + l16) * 32 + quad * 8);
#pragma unroll
        for (int j = 0; j < 4; ++j)
            bfr[j] = *reinterpret_cast<const bf16x8*>(Bs + (wn + j * 16 + l16) * 32 + quad * 8);
#pragma unroll
        for (int i = 0; i < 4; ++i)
#pragma unroll
            for (int j = 0; j < 4; ++j)
                acc[i][j] = __builtin_amdgcn_mfma_f32_16x16x32_bf16(af[i], bfr[j], acc[i][j], 0, 0, 0);
    }

    if (zi < 2) {
        unsigned short* C = (zi == 0) ? q : k;
#pragma unroll
        for (int i = 0; i < 4; ++i)
#pragma unroll
            for (int j = 0; j < 4; ++j) {
                const int gcol = n0 + wn + j * 16 + l16;
#pragma unroll
                for (int reg = 0; reg < 4; ++reg) {
                    const int grow = m0 + wm + i * 16 + quad * 4 + reg;
                    C[(size_t)grow * D + gcol] = f2bf(acc[i][j][reg]);
                }
            }
    } else {
        const int b = m0 >> 10;
#pragma unroll
        for (int i = 0; i < 4; ++i)
#pragma unroll
            for (int j = 0; j < 4; ++j) {
                const int gcol = n0 + wn + j * 16 + l16;          // flat D index = h*64+dh
                const int srow0 = (m0 - b * S) + wm + i * 16 + quad * 4;
                ushort4 h;
                h.x = f2bf(acc[i][j][0]); h.y = f2bf(acc[i][j][1]);
                h.z = f2bf(acc[i][j][2]); h.w = f2bf(acc[i][j][3]);
                *reinterpret_cast<ushort4*>(vT + ((size_t)b * D + gcol) * S + srow0) = h;
            }
    }
}

// ------- Kernel 3: single-pass fused attention, LDS-resident P -------
// Grid: (1, S/64, H*B). Block 512 = 8 waves.
// Wave w: rowg = w&3 (16 q-rows rowg*16..+15), khalf = w>>2 (keys kt {2kh,2kh+1}).
// O accumulated UNNORMALIZED, scaled by 1/rsum at the end; P kept as bf16 in LDS
// (swizzled) and written to A in an epilogue as bf16(e)*sL.
// K(t+1) prefetched to registers (T14), V(t+1) via global_load_lds double-buffer;
// raw s_barrier + explicit waitcnts keep prefetches in flight across barriers.
__global__ __launch_bounds__(512, 2) void attn_fused_kernel(
    const unsigned short* __restrict__ q, const unsigned short* __restrict__ k,
    const unsigned short* __restrict__ vT, float* __restrict__ Aout,
    float* __restrict__ O)
{
    __shared__ unsigned short Ks[2 * 64 * 32];   // [c][key][32dh], XOR-swizzled (8 KB)
    __shared__ unsigned short Vs[2][4 * 64 * 16];// dbuf [kt][dh][16keys], linear (16 KB)
    __shared__ unsigned short Ps[64 * 1024];     // [qrow][key] bf16, XOR-swizzled (128 KB)
    __shared__ float sred[2 * 64];               // [khalf][row] partial denominators
    __shared__ float sinv[64];                   // 1/rsum per row

    const int z = blockIdx.z;            // z = h*B + b (head-major A layout)
    const int b = z & 1, h = z >> 1;
    const int m0 = blockIdx.y * 64;
    const int t = threadIdx.x;           // 0..511
    const int w = t >> 6, lane = t & 63;
    const int quad = lane >> 4, l16 = lane & 15;
    const int rowg = w & 3, khalf = w >> 2;
    const int kt0 = khalf * 2;
    const int prow = rowg * 16 + l16;    // this lane's q-row within the block

    // K staging geometry: 512 threads cover the 64x64 bf16 tile, 16B each.
    const int ksr = t >> 3;              // key 0..63
    const int ksc = (t & 7) * 8;         // dh 0..56
    const unsigned short* kbase = k + (size_t)(b * S + ksr) * D + h * DH + ksc;
    // LDS byte addr (swizzle F(key) = (((key>>1)&3)<<1 | ((key>>3)&1)) << 4):
    const int kwaddr = (((ksc >> 5) * 4096) + ksr * 64 + (ksc & 31) * 2)
                     ^ (((((ksr >> 1) & 3) << 1) | ((ksr >> 3) & 1)) << 4);
    const int kxorR = ((((l16 >> 1) & 3) << 1) | ((l16 >> 3) & 1)) << 4;

    // V staging geometry: 512 threads cover [4kt][64dh][16keys], 16B each (lds off = t*16).
    const int vkt = t >> 7, vdh = (t >> 1) & 63, vkh = t & 1;
    const unsigned short* vbase = vT + ((size_t)b * D + h * DH + vdh) * S + vkt * 16 + vkh * 8;

    // Q fragments straight from global (one-time 16B x2 per lane)
    const unsigned short* qrow = q + (size_t)(b * S + m0 + prow) * D + h * DH;
    bf16x8 qf[2];
    qf[0] = *reinterpret_cast<const bf16x8*>(qrow + quad * 8);
    qf[1] = *reinterpret_cast<const bf16x8*>(qrow + 32 + quad * 8);

    // ---- prologue: stage K(0) via regs, V(0) via global_load_lds ----
    {
        uint4 kreg = *reinterpret_cast<const uint4*>(kbase);
        __builtin_amdgcn_global_load_lds((gptr_t)vbase, (lptr_t)((char*)Vs[0] + t * 16), 16, 0, 0);
        asm volatile("s_waitcnt vmcnt(0)" ::: "memory");
        *reinterpret_cast<uint4*>((char*)Ks + kwaddr) = kreg;
        asm volatile("s_waitcnt lgkmcnt(0)" ::: "memory");
        __builtin_amdgcn_s_barrier();
        __builtin_amdgcn_sched_barrier(0);
    }

    f32x4 accO[4];
#pragma unroll
    for (int jj = 0; jj < 4; ++jj) accO[jj] = (f32x4){0.f, 0.f, 0.f, 0.f};
    float rsum = 0.f;
    int cur = 0;

    for (int tt = 0; tt < 16; ++tt) {
        const int n0 = tt * 64;
        const bool pf = (tt < 15);
        uint4 kreg;
        if (pf) {
            kreg = *reinterpret_cast<const uint4*>(kbase + (size_t)(n0 + 64) * D);  // K(t+1)->reg
            __builtin_amdgcn_global_load_lds((gptr_t)(vbase + n0 + 64),
                                             (lptr_t)((char*)Vs[cur ^ 1] + t * 16), 16, 0, 0);
        }
        // ---- compute on Ks (tile t) and Vs[cur] ----
#pragma unroll
        for (int kk = 0; kk < 2; ++kk) {
            const int kt = kt0 + kk;
            const int key = kt * 16 + l16;
            f32x4 a = (f32x4){0.f, 0.f, 0.f, 0.f};
#pragma unroll
            for (int c = 0; c < 2; ++c) {
                const int kraddr = (c * 4096 + key * 64 + quad * 16) ^ kxorR;
                bf16x8 kf = *reinterpret_cast<const bf16x8*>((const char*)Ks + kraddr);
                a = __builtin_amdgcn_mfma_f32_16x16x32_bf16(kf, qf[c], a, 0, 0, 0);
            }
            const float e0 = __expf(a[0] * 0.125f);
            const float e1 = __expf(a[1] * 0.125f);
            const float e2 = __expf(a[2] * 0.125f);
            const float e3 = __expf(a[3] * 0.125f);
            rsum += (e0 + e1) + (e2 + e3);
            bf16x4 p;
            p[0] = (short)f2bf(e0); p[1] = (short)f2bf(e1);
            p[2] = (short)f2bf(e2); p[3] = (short)f2bf(e3);
            // stash P (unnormalized) in LDS for the A epilogue
            const int pw = (prow * 2048 + (n0 + kt * 16 + quad * 4) * 2) ^ ((prow & 7) << 4);
            *reinterpret_cast<bf16x4*>((char*)Ps + pw) = p;
            // PV accumulate (unnormalized)
#pragma unroll
            for (int jj = 0; jj < 4; ++jj) {
                bf16x4 vv = *reinterpret_cast<const bf16x4*>(
                    (const char*)Vs[cur] + kt * 2048 + (jj * 16 + l16) * 32 + quad * 8);
                accO[jj] = __builtin_amdgcn_mfma_f32_16x16x16bf16_1k(p, vv, accO[jj], 0, 0, 0);
            }
        }
        // everyone done reading Ks(t) / Vs[cur]
        asm volatile("s_waitcnt lgkmcnt(0)" ::: "memory");
        __builtin_amdgcn_s_barrier();
        __builtin_amdgcn_sched_barrier(0);
        if (pf) {
            asm volatile("s_waitcnt vmcnt(0)" ::: "memory");   // kreg + V(t+1) arrived
            *reinterpret_cast<uint4*>((char*)Ks + kwaddr) = kreg;
            asm volatile("s_waitcnt lgkmcnt(0)" ::: "memory");
            __builtin_amdgcn_s_barrier();
            __builtin_amdgcn_sched_barrier(0);
        }
        cur ^= 1;
    }

    // ---- denominator: combine the two key-halves ----
    rsum += __shfl_xor(rsum, 16, 64);
    rsum += __shfl_xor(rsum, 32, 64);
    if (lane < 16) sred[khalf * 64 + rowg * 16 + lane] = rsum;
    __syncthreads();
    if (khalf == 0 && lane < 16) {
        const float tot = sred[rowg * 16 + lane] + sred[64 + rowg * 16 + lane];
        sinv[rowg * 16 + lane] = 1.0f / tot;
    }
    __syncthreads();

    // ---- A epilogue: wave w writes rows w*8 .. w*8+7 (normalized) ----
    {
        float* Az = Aout + (size_t)z * S * S + (size_t)m0 * S;
#pragma unroll
        for (int r8 = 0; r8 < 8; ++r8) {
            const int row = w * 8 + r8;
            const float sc = sinv[row];
            const int swz = (row & 7) << 4;
            const int base = row * 2048 + lane * 16;
            uint4 h0 = *reinterpret_cast<const uint4*>((const char*)Ps + (base ^ swz));
            uint4 h1 = *reinterpret_cast<const uint4*>((const char*)Ps + ((base + 1024) ^ swz));
            float* dst = Az + (size_t)row * S + lane * 8;
            float4 fa, fb, fc, fd;
            fa.x = bflo(h0.x) * sc; fa.y = bfhi(h0.x) * sc;
            fa.z = bflo(h0.y) * sc; fa.w = bfhi(h0.y) * sc;
            fb.x = bflo(h0.z) * sc; fb.y = bfhi(h0.z) * sc;
            fb.z = bflo(h0.w) * sc; fb.w = bfhi(h0.w) * sc;
            fc.x = bflo(h1.x) * sc; fc.y = bfhi(h1.x) * sc;
            fc.z = bflo(h1.y) * sc; fc.w = bfhi(h1.y) * sc;
            fd.x = bflo(h1.z) * sc; fd.y = bfhi(h1.z) * sc;
            fd.z = bflo(h1.w) * sc; fd.w = bfhi(h1.w) * sc;
            *reinterpret_cast<float4*>(dst)       = fa;
            *reinterpret_cast<float4*>(dst + 4)   = fb;
            *reinterpret_cast<float4*>(dst + 512) = fc;
            *reinterpret_cast<float4*>(dst + 516) = fd;
        }
    }
    __syncthreads();   // Ps free -> reuse as accO combine buffer

    float* obuf = reinterpret_cast<float*>(Ps);
    if (khalf == 1) {
#pragma unroll
        for (int jj = 0; jj < 4; ++jj)
#pragma unroll
            for (int r = 0; r < 4; ++r)
                obuf[rowg * 1024 + (quad * 4 + r) * 64 + jj * 16 + l16] = accO[jj][r];
    }
    __syncthreads();
    if (khalf == 0) {
#pragma unroll
        for (int jj = 0; jj < 4; ++jj)
#pragma unroll
            for (int r = 0; r < 4; ++r) {
                const int lrow = rowg * 16 + quad * 4 + r;
                const float o = accO[jj][r]
                              + obuf[rowg * 1024 + (quad * 4 + r) * 64 + jj * 16 + l16];
                O[(size_t)(b * S + m0 + lrow) * D + h * DH + jj * 16 + l16] = o * sinv[lrow];
            }
    }
}

// ---------------- Kernel 4: out = LN(id_ln+O,g1,b1) + LN(id+O,g2,b2) ----------
__global__ __launch_bounds__(256) void final_kernel(
    const float* __restrict__ id, const float* __restrict__ id_ln, const float* __restrict__ O,
    const float* __restrict__ g1, const float* __restrict__ b1,
    const float* __restrict__ g2, const float* __restrict__ b2,
    float* __restrict__ out)
{
    __shared__ float sm[16];
    __shared__ float stats[4];
    const int row = blockIdx.x;
    const int t = threadIdx.x;
    const size_t base = (size_t)row * D;
    const float4 xi = reinterpret_cast<const float4*>(id + base)[t];
    const float4 xl = reinterpret_cast<const float4*>(id_ln + base)[t];
    const float4 xo = reinterpret_cast<const float4*>(O + base)[t];
    float4 t1, t2;
    t1.x = xl.x + xo.x; t1.y = xl.y + xo.y; t1.z = xl.z + xo.z; t1.w = xl.w + xo.w;
    t2.x = xi.x + xo.x; t2.y = xi.y + xo.y; t2.z = xi.z + xo.z; t2.w = xi.w + xo.w;
    float s1  = t1.x + t1.y + t1.z + t1.w;
    float ss1 = t1.x*t1.x + t1.y*t1.y + t1.z*t1.z + t1.w*t1.w;
    float s2  = t2.x + t2.y + t2.z + t2.w;
    float ss2 = t2.x*t2.x + t2.y*t2.y + t2.z*t2.z + t2.w*t2.w;
    s1 = wave_sum(s1); ss1 = wave_sum(ss1);
    s2 = wave_sum(s2); ss2 = wave_sum(ss2);
    const int lane = t & 63, wid = t >> 6;
    if (lane == 0) { sm[wid] = s1; sm[4+wid] = ss1; sm[8+wid] = s2; sm[12+wid] = ss2; }
    __syncthreads();
    if (t == 0) {
        float S1 = sm[0]+sm[1]+sm[2]+sm[3];
        float Q1 = sm[4]+sm[5]+sm[6]+sm[7];
        float S2 = sm[8]+sm[9]+sm[10]+sm[11];
        float Q2 = sm[12]+sm[13]+sm[14]+sm[15];
        float m1 = S1 * (1.0f / D);
        float m2 = S2 * (1.0f / D);
        stats[0] = m1; stats[1] = rsqrtf(Q1 * (1.0f / D) - m1*m1 + EPS);
        stats[2] = m2; stats[3] = rsqrtf(Q2 * (1.0f / D) - m2*m2 + EPS);
    }
    __syncthreads();
    const float m1 = stats[0], r1 = stats[1], m2 = stats[2], r2 = stats[3];
    const float4 g1v = reinterpret_cast<const float4*>(g1)[t];
    const float4 b1v = reinterpret_cast<const float4*>(b1)[t];
    const float4 g2v = reinterpret_cast<const float4*>(g2)[t];
    const float4 b2v = reinterpret_cast<const float4*>(b2)[t];
    float4 o;
    o.x = (t1.x - m1)*r1*g1v.x + b1v.x + (t2.x - m2)*r2*g2v.x + b2v.x;
    o.y = (t1.y - m1)*r1*g1v.y + b1v.y + (t2.y - m2)*r2*g2v.y + b2v.y;
    o.z = (t1.z - m1)*r1*g1v.z + b1v.z + (t2.z - m2)*r2*g2v.z + b2v.z;
    o.w = (t1.w - m1)*r1*g1v.w + b1v.w + (t2.w - m2)*r2*g2v.w + b2v.w;
    reinterpret_cast<float4*>(out + base)[t] = o;
}

}  // namespace

extern "C" void kernel_launch(void* const* d_in, const int* in_sizes, int n_in,
                              void* d_out, int out_size, void* d_ws, size_t ws_size,
                              hipStream_t stream)
{
    const float* id = (const float*)d_in[0];
    const float* Wq = (const float*)d_in[1];
    const float* Wk = (const float*)d_in[2];
    const float* Wv = (const float*)d_in[3];
    const float* g0 = (const float*)d_in[4];
    const float* b0 = (const float*)d_in[5];
    const float* g1 = (const float*)d_in[6];
    const float* b1 = (const float*)d_in[7];
    const float* g2 = (const float*)d_in[8];
    const float* b2 = (const float*)d_in[9];

    float* out  = (float*)d_out;
    float* Aout = out + (size_t)B * S * D;   // A region [H*B, S, S], written once by attn

    char* ws = (char*)d_ws;
    float* id_ln  = (float*)(ws);                          //  8 MiB fp32
    float* O      = (float*)(ws + (8u << 20));             //  8 MiB fp32
    unsigned short* idln_bf = (unsigned short*)(ws + (16u << 20)); // 4 MiB
    unsigned short* Wb      = idln_bf + (size_t)M * D;     //  6 MiB (3 x DxD bf16)
    unsigned short* qb      = Wb + (size_t)3 * D * D;      //  4 MiB
    unsigned short* kb      = qb + (size_t)M * D;          //  4 MiB
    unsigned short* vT      = kb + (size_t)M * D;          //  4 MiB  [B][D][S]

    hipLaunchKernelGGL(cvt_w_kernel, dim3(D * D / 1024, 1, 3), dim3(256), 0, stream,
                       Wq, Wk, Wv, Wb);
    hipLaunchKernelGGL(ln0_kernel, dim3(M), dim3(256), 0, stream, id, g0, b0, id_ln, idln_bf);
    hipLaunchKernelGGL(qkv_mfma_kernel, dim3(D / 128, M / 128, 3), dim3(256), 0, stream,
                       idln_bf, Wb, qb, kb, vT);
    hipLaunchKernelGGL(attn_fused_kernel, dim3(1, S / 64, H * B), dim3(512), 0, stream,
                       qb, kb, vT, Aout, O);
    hipLaunchKernelGGL(final_kernel, dim3(M), dim3(256), 0, stream,
                       id, id_ln, O, g1, b1, g2, b2, out);
}

// Round 2
// 250.664 us; speedup vs baseline: 1.0084x; 1.0084x over previous
//
#include <hip/hip_runtime.h>

namespace {

constexpr int B = 2, S = 1024, D = 1024, H = 16, DH = 64;
constexpr int M = B * S;  // 2048 rows
constexpr float EPS = 1e-5f;

using bf16x8 = __attribute__((ext_vector_type(8))) short;  // MFMA A/B frag, K=32 (4 VGPRs)
using bf16x4 = __attribute__((ext_vector_type(4))) short;  // MFMA A/B frag, K=16 (2 VGPRs)
using f32x4  = __attribute__((ext_vector_type(4))) float;  // MFMA C/D frag

typedef const __attribute__((address_space(1))) void* gptr_t;
typedef __attribute__((address_space(3))) void* lptr_t;

__device__ __forceinline__ unsigned short f2bf(float f) {
    union { float f; unsigned u; } v{f};
    unsigned r = v.u + 0x7fffu + ((v.u >> 16) & 1u);  // RNE
    return (unsigned short)(r >> 16);
}

__device__ __forceinline__ float wave_sum(float v) {
#pragma unroll
    for (int off = 32; off > 0; off >>= 1) v += __shfl_down(v, off, 64);
    return v;
}

// ---------------- Kernel 0: W fp32 -> bf16 ----------------
__global__ __launch_bounds__(256) void cvt_w_kernel(
    const float* __restrict__ Wq, const float* __restrict__ Wk,
    const float* __restrict__ Wv, unsigned short* __restrict__ Wb)
{
    const float* src = (blockIdx.z == 0) ? Wq : (blockIdx.z == 1) ? Wk : Wv;
    const size_t i = ((size_t)blockIdx.x * 256 + threadIdx.x) * 4;
    float4 f = *reinterpret_cast<const float4*>(src + i);
    ushort4 h;
    h.x = f2bf(f.x); h.y = f2bf(f.y); h.z = f2bf(f.z); h.w = f2bf(f.w);
    *reinterpret_cast<ushort4*>(Wb + (size_t)blockIdx.z * D * D + i) = h;
}

// ---------------- Kernel 1: LN(id) -> id_ln (fp32 + bf16) ----------------
__global__ __launch_bounds__(256) void ln0_kernel(
    const float* __restrict__ x, const float* __restrict__ g,
    const float* __restrict__ bt, float* __restrict__ y,
    unsigned short* __restrict__ yb)
{
    __shared__ float sm[8];
    __shared__ float stats[2];
    const int row = blockIdx.x;
    const int t = threadIdx.x;
    const float4 v = reinterpret_cast<const float4*>(x + (size_t)row * D)[t];
    float s  = v.x + v.y + v.z + v.w;
    float ss = v.x*v.x + v.y*v.y + v.z*v.z + v.w*v.w;
    s = wave_sum(s); ss = wave_sum(ss);
    const int lane = t & 63, wid = t >> 6;
    if (lane == 0) { sm[wid] = s; sm[4 + wid] = ss; }
    __syncthreads();
    if (t == 0) {
        float S1 = sm[0] + sm[1] + sm[2] + sm[3];
        float S2 = sm[4] + sm[5] + sm[6] + sm[7];
        float m  = S1 * (1.0f / D);
        float var = S2 * (1.0f / D) - m * m;
        stats[0] = m; stats[1] = rsqrtf(var + EPS);
    }
    __syncthreads();
    const float m = stats[0], r = stats[1];
    const float4 gv = reinterpret_cast<const float4*>(g)[t];
    const float4 bv = reinterpret_cast<const float4*>(bt)[t];
    float4 o;
    o.x = (v.x - m) * r * gv.x + bv.x;
    o.y = (v.y - m) * r * gv.y + bv.y;
    o.z = (v.z - m) * r * gv.z + bv.z;
    o.w = (v.w - m) * r * gv.w + bv.w;
    reinterpret_cast<float4*>(y + (size_t)row * D)[t] = o;
    ushort4 h; h.x = f2bf(o.x); h.y = f2bf(o.y); h.z = f2bf(o.z); h.w = f2bf(o.w);
    *reinterpret_cast<ushort4*>(yb + (size_t)row * D + t * 4) = h;
}

// ---------------- Kernel 2: q/k/v = id_ln @ W^T, bf16 MFMA 128x128 ----------
// 2-phase double-buffered staging: STAGE(t+1) issued before compute(t), one
// __syncthreads per K-step (drain = vmcnt(0)+lgkmcnt(0)+barrier).
__global__ __launch_bounds__(256) void qkv_mfma_kernel(
    const unsigned short* __restrict__ idln, const unsigned short* __restrict__ Wb,
    unsigned short* __restrict__ q, unsigned short* __restrict__ k,
    unsigned short* __restrict__ vT)
{
    __shared__ unsigned short As[2][128 * 32];
    __shared__ unsigned short Bs[2][128 * 32];
    const int zi = blockIdx.z;
    const unsigned short* Bmat = Wb + (size_t)zi * D * D;
    const int m0 = blockIdx.y * 128, n0 = blockIdx.x * 128;
    const int t = threadIdx.x;
    const int w = t >> 6, lane = t & 63;
    const int wm = (w >> 1) * 64, wn = (w & 1) * 64;
    const int quad = lane >> 4, l16 = lane & 15;
    const int srow = t >> 2;          // 0..63
    const int scol = (t & 3) * 8;     // 0,8,16,24 (bf16 elems)

    f32x4 acc[4][4];
#pragma unroll
    for (int i = 0; i < 4; ++i)
#pragma unroll
        for (int j = 0; j < 4; ++j) acc[i][j] = (f32x4){0.f, 0.f, 0.f, 0.f};

    auto STAGE = [&](int kk0, int bb) {
#pragma unroll
        for (int c = 0; c < 2; ++c) {
            const unsigned short* ga = idln + (size_t)(m0 + srow + c * 64) * D + kk0 + scol;
            __builtin_amdgcn_global_load_lds((gptr_t)ga, (lptr_t)(As[bb] + t * 8 + c * 2048), 16, 0, 0);
            const unsigned short* gb = Bmat + (size_t)(n0 + srow + c * 64) * D + kk0 + scol;
            __builtin_amdgcn_global_load_lds((gptr_t)gb, (lptr_t)(Bs[bb] + t * 8 + c * 2048), 16, 0, 0);
        }
    };

    STAGE(0, 0);
    __syncthreads();
    int cur = 0;
    for (int k0 = 0; k0 < D; k0 += 32) {
        if (k0 + 32 < D) STAGE(k0 + 32, cur ^ 1);
        bf16x8 af[4], bfr[4];
#pragma unroll
        for (int i = 0; i < 4; ++i)
            af[i] = *reinterpret_cast<const bf16x8*>(As[cur] + (wm + i * 16 + l16) * 32 + quad * 8);
#pragma unroll
        for (int j = 0; j < 4; ++j)
            bfr[j] = *reinterpret_cast<const bf16x8*>(Bs[cur] + (wn + j * 16 + l16) * 32 + quad * 8);
#pragma unroll
        for (int i = 0; i < 4; ++i)
#pragma unroll
            for (int j = 0; j < 4; ++j)
                acc[i][j] = __builtin_amdgcn_mfma_f32_16x16x32_bf16(af[i], bfr[j], acc[i][j], 0, 0, 0);
        __syncthreads();
        cur ^= 1;
    }

    if (zi < 2) {
        unsigned short* C = (zi == 0) ? q : k;
#pragma unroll
        for (int i = 0; i < 4; ++i)
#pragma unroll
            for (int j = 0; j < 4; ++j) {
                const int gcol = n0 + wn + j * 16 + l16;
#pragma unroll
                for (int reg = 0; reg < 4; ++reg) {
                    const int grow = m0 + wm + i * 16 + quad * 4 + reg;
                    C[(size_t)grow * D + gcol] = f2bf(acc[i][j][reg]);
                }
            }
    } else {
        const int b = m0 >> 10;
#pragma unroll
        for (int i = 0; i < 4; ++i)
#pragma unroll
            for (int j = 0; j < 4; ++j) {
                const int gcol = n0 + wn + j * 16 + l16;          // flat D index = h*64+dh
                const int srow0 = (m0 - b * S) + wm + i * 16 + quad * 4;
                ushort4 h;
                h.x = f2bf(acc[i][j][0]); h.y = f2bf(acc[i][j][1]);
                h.z = f2bf(acc[i][j][2]); h.w = f2bf(acc[i][j][3]);
                *reinterpret_cast<ushort4*>(vT + ((size_t)b * D + gcol) * S + srow0) = h;
            }
    }
}

// ------- Kernel 3: fused attention, two-pass, swizzled LDS + 2-phase dbuf -------
// Grid: (1, S/64, H*B). Block 256 = 4 waves; wave w owns q-rows m0+w*16..+15.
// K tile [c][key][32dh]: 16B-slot XOR-swizzle by (key>>1)&3 (8-way -> 2-way, free).
// V tile [kt][dh][16keys]: 8B-granule XOR-swizzle by ((dh>>2)&1)<<1 (4-way -> 2-way).
// Both swizzles applied as pre-swizzled GLOBAL source + swizzled LDS read
// (global_load_lds dest must stay linear, rule #21).
__global__ __launch_bounds__(256) void attn_fused_kernel(
    const unsigned short* __restrict__ q, const unsigned short* __restrict__ k,
    const unsigned short* __restrict__ vT, float* __restrict__ Aout,
    float* __restrict__ O)
{
    __shared__ unsigned short Qs[2 * 64 * 32];       // [c][qrow][32dh], linear (8 KB)
    __shared__ unsigned short Ks[2][2 * 64 * 32];    // dbuf [c][key][32dh], swizzled (16 KB)
    __shared__ unsigned short Vs[2][4 * 64 * 16];    // dbuf [kt][dh][16keys], swizzled (16 KB)

    const int z = blockIdx.z;            // z = h*B + b (head-major A layout)
    const int b = z & 1, h = z >> 1;
    const int m0 = blockIdx.y * 64;
    const int t = threadIdx.x;
    const int w = t >> 6, lane = t & 63;
    const int quad = lane >> 4, l16 = lane & 15;

    // K/Q staging geometry: thread t covers (row = t>>2, 16B slot = t&3)
    const int ksr = t >> 2;
    const int kslot = t & 3;
    const int ksc = (kslot ^ ((ksr >> 1) & 3)) * 8;  // pre-swizzled source column (K only)
    // V staging geometry: per c2 half, kt = c2*2+(t>>7), dh = (t>>1)&63, kh = t&1
    const int vdh = (t >> 1) & 63, vkh = t & 1;
    const int vkh_src = vkh ^ ((vdh >> 2) & 1);      // pre-swizzled source key-half

    // Read-side swizzle offsets (loop-invariant):
    const int kx = (quad ^ ((l16 >> 1) & 3)) * 16;                 // K frag byte slot
    const int vx = (quad * 8) ^ (((l16 >> 2) & 1) << 4);           // V frag byte granule

    auto STAGE_K = [&](int nt, int bb) {
#pragma unroll
        for (int c = 0; c < 2; ++c) {
            const unsigned short* gk = k + (size_t)(b * S + nt + ksr) * D + h * DH + c * 32 + ksc;
            __builtin_amdgcn_global_load_lds((gptr_t)gk, (lptr_t)(Ks[bb] + c * 2048 + t * 8), 16, 0, 0);
        }
    };
    auto STAGE_V = [&](int nt, int bb) {
#pragma unroll
        for (int c2 = 0; c2 < 2; ++c2) {
            const int kt = c2 * 2 + (t >> 7);
            const unsigned short* gv = vT + ((size_t)b * D + h * DH + vdh) * S + nt + kt * 16 + vkh_src * 8;
            __builtin_amdgcn_global_load_lds((gptr_t)gv, (lptr_t)((char*)Vs[bb] + c2 * 4096 + t * 16), 16, 0, 0);
        }
    };

    // ---- prologue: stage Q (once, linear) and K(0) ----
#pragma unroll
    for (int c = 0; c < 2; ++c) {
        const unsigned short* gq = q + (size_t)(b * S + m0 + ksr) * D + h * DH + c * 32 + kslot * 8;
        __builtin_amdgcn_global_load_lds((gptr_t)gq, (lptr_t)(Qs + c * 2048 + t * 8), 16, 0, 0);
    }
    STAGE_K(0, 0);
    __syncthreads();
    // hoist Q B-frags (q = w*16 + l16, dh = c*32 + quad*8..+7); one-time conflict OK
    bf16x8 qf[2];
#pragma unroll
    for (int c = 0; c < 2; ++c)
        qf[c] = *reinterpret_cast<const bf16x8*>(Qs + c * 2048 + (w * 16 + l16) * 32 + quad * 8);

    // ---------------- pass 1: row sums of exp(qk/8) ----------------
    float rsum = 0.f;
    int cur = 0;
    for (int tt = 0; tt < 16; ++tt) {
        if (tt < 15) STAGE_K((tt + 1) * 64, cur ^ 1);
#pragma unroll
        for (int kt = 0; kt < 4; ++kt) {
            f32x4 a = (f32x4){0.f, 0.f, 0.f, 0.f};
#pragma unroll
            for (int c = 0; c < 2; ++c) {
                bf16x8 kf = *reinterpret_cast<const bf16x8*>(
                    (const char*)Ks[cur] + c * 4096 + (kt * 16 + l16) * 64 + kx);
                a = __builtin_amdgcn_mfma_f32_16x16x32_bf16(kf, qf[c], a, 0, 0, 0);
            }
#pragma unroll
            for (int r = 0; r < 4; ++r) rsum += __expf(a[r] * 0.125f);
        }
        __syncthreads();
        cur ^= 1;
    }
    // cur == 0 again here. Stage pass-2 tile 0 while reducing the denominator.
    STAGE_K(0, 0);
    STAGE_V(0, 0);
    rsum += __shfl_xor(rsum, 16, 64);
    rsum += __shfl_xor(rsum, 32, 64);
    const float sL = 1.0f / rsum;   // full row sum for q-row l16, every lane

    f32x4 accO[4];
#pragma unroll
    for (int jj = 0; jj < 4; ++jj) accO[jj] = (f32x4){0.f, 0.f, 0.f, 0.f};
    float* Az = Aout + (size_t)z * S * S + (size_t)(m0 + w * 16 + l16) * S;
    __syncthreads();

    // ---------------- pass 2: recompute, write A (normalized), accumulate O ----
    cur = 0;
    for (int tt = 0; tt < 16; ++tt) {
        const int n0 = tt * 64;
        if (tt < 15) { STAGE_K(n0 + 64, cur ^ 1); STAGE_V(n0 + 64, cur ^ 1); }
#pragma unroll
        for (int kt = 0; kt < 4; ++kt) {
            f32x4 a = (f32x4){0.f, 0.f, 0.f, 0.f};
#pragma unroll
            for (int c = 0; c < 2; ++c) {
                bf16x8 kf = *reinterpret_cast<const bf16x8*>(
                    (const char*)Ks[cur] + c * 4096 + (kt * 16 + l16) * 64 + kx);
                a = __builtin_amdgcn_mfma_f32_16x16x32_bf16(kf, qf[c], a, 0, 0, 0);
            }
            float e0 = __expf(a[0] * 0.125f) * sL;
            float e1 = __expf(a[1] * 0.125f) * sL;
            float e2 = __expf(a[2] * 0.125f) * sL;
            float e3 = __expf(a[3] * 0.125f) * sL;
            // write final A: lane's q-row, keys n0+kt*16+quad*4 .. +3 (16B store)
            *reinterpret_cast<float4*>(Az + n0 + kt * 16 + quad * 4) = make_float4(e0, e1, e2, e3);
            // pack P a-frag for x16 MFMA: A[m=q=l16][k=key=quad*4+j]
            bf16x4 p;
            p[0] = (short)f2bf(e0); p[1] = (short)f2bf(e1);
            p[2] = (short)f2bf(e2); p[3] = (short)f2bf(e3);
#pragma unroll
            for (int jj = 0; jj < 4; ++jj) {
                bf16x4 vv = *reinterpret_cast<const bf16x4*>(
                    (const char*)Vs[cur] + kt * 2048 + (jj * 16 + l16) * 32 + vx);
                accO[jj] = __builtin_amdgcn_mfma_f32_16x16x16bf16_1k(p, vv, accO[jj], 0, 0, 0);
            }
        }
        __syncthreads();
        cur ^= 1;
    }
    // write O: D row = q = quad*4+r (within wave's 16 rows), col dh = jj*16+l16
#pragma unroll
    for (int jj = 0; jj < 4; ++jj)
#pragma unroll
        for (int r = 0; r < 4; ++r) {
            const int grow = b * S + m0 + w * 16 + quad * 4 + r;
            O[(size_t)grow * D + h * DH + jj * 16 + l16] = accO[jj][r];
        }
}

// ---------------- Kernel 4: out = LN(id_ln+O,g1,b1) + LN(id+O,g2,b2) ----------
__global__ __launch_bounds__(256) void final_kernel(
    const float* __restrict__ id, const float* __restrict__ id_ln, const float* __restrict__ O,
    const float* __restrict__ g1, const float* __restrict__ b1,
    const float* __restrict__ g2, const float* __restrict__ b2,
    float* __restrict__ out)
{
    __shared__ float sm[16];
    __shared__ float stats[4];
    const int row = blockIdx.x;
    const int t = threadIdx.x;
    const size_t base = (size_t)row * D;
    const float4 xi = reinterpret_cast<const float4*>(id + base)[t];
    const float4 xl = reinterpret_cast<const float4*>(id_ln + base)[t];
    const float4 xo = reinterpret_cast<const float4*>(O + base)[t];
    float4 t1, t2;
    t1.x = xl.x + xo.x; t1.y = xl.y + xo.y; t1.z = xl.z + xo.z; t1.w = xl.w + xo.w;
    t2.x = xi.x + xo.x; t2.y = xi.y + xo.y; t2.z = xi.z + xo.z; t2.w = xi.w + xo.w;
    float s1  = t1.x + t1.y + t1.z + t1.w;
    float ss1 = t1.x*t1.x + t1.y*t1.y + t1.z*t1.z + t1.w*t1.w;
    float s2  = t2.x + t2.y + t2.z + t2.w;
    float ss2 = t2.x*t2.x + t2.y*t2.y + t2.z*t2.z + t2.w*t2.w;
    s1 = wave_sum(s1); ss1 = wave_sum(ss1);
    s2 = wave_sum(s2); ss2 = wave_sum(ss2);
    const int lane = t & 63, wid = t >> 6;
    if (lane == 0) { sm[wid] = s1; sm[4+wid] = ss1; sm[8+wid] = s2; sm[12+wid] = ss2; }
    __syncthreads();
    if (t == 0) {
        float S1 = sm[0]+sm[1]+sm[2]+sm[3];
        float Q1 = sm[4]+sm[5]+sm[6]+sm[7];
        float S2 = sm[8]+sm[9]+sm[10]+sm[11];
        float Q2 = sm[12]+sm[13]+sm[14]+sm[15];
        float m1 = S1 * (1.0f / D);
        float m2 = S2 * (1.0f / D);
        stats[0] = m1; stats[1] = rsqrtf(Q1 * (1.0f / D) - m1*m1 + EPS);
        stats[2] = m2; stats[3] = rsqrtf(Q2 * (1.0f / D) - m2*m2 + EPS);
    }
    __syncthreads();
    const float m1 = stats[0], r1 = stats[1], m2 = stats[2], r2 = stats[3];
    const float4 g1v = reinterpret_cast<const float4*>(g1)[t];
    const float4 b1v = reinterpret_cast<const float4*>(b1)[t];
    const float4 g2v = reinterpret_cast<const float4*>(g2)[t];
    const float4 b2v = reinterpret_cast<const float4*>(b2)[t];
    float4 o;
    o.x = (t1.x - m1)*r1*g1v.x + b1v.x + (t2.x - m2)*r2*g2v.x + b2v.x;
    o.y = (t1.y - m1)*r1*g1v.y + b1v.y + (t2.y - m2)*r2*g2v.y + b2v.y;
    o.z = (t1.z - m1)*r1*g1v.z + b1v.z + (t2.z - m2)*r2*g2v.z + b2v.z;
    o.w = (t1.w - m1)*r1*g1v.w + b1v.w + (t2.w - m2)*r2*g2v.w + b2v.w;
    reinterpret_cast<float4*>(out + base)[t] = o;
}

}  // namespace

extern "C" void kernel_launch(void* const* d_in, const int* in_sizes, int n_in,
                              void* d_out, int out_size, void* d_ws, size_t ws_size,
                              hipStream_t stream)
{
    const float* id = (const float*)d_in[0];
    const float* Wq = (const float*)d_in[1];
    const float* Wk = (const float*)d_in[2];
    const float* Wv = (const float*)d_in[3];
    const float* g0 = (const float*)d_in[4];
    const float* b0 = (const float*)d_in[5];
    const float* g1 = (const float*)d_in[6];
    const float* b1 = (const float*)d_in[7];
    const float* g2 = (const float*)d_in[8];
    const float* b2 = (const float*)d_in[9];

    float* out  = (float*)d_out;
    float* Aout = out + (size_t)B * S * D;   // A region [H*B, S, S], written once by attn

    char* ws = (char*)d_ws;
    float* id_ln  = (float*)(ws);                          //  8 MiB fp32
    float* O      = (float*)(ws + (8u << 20));             //  8 MiB fp32
    unsigned short* idln_bf = (unsigned short*)(ws + (16u << 20)); // 4 MiB
    unsigned short* Wb      = idln_bf + (size_t)M * D;     //  6 MiB (3 x DxD bf16)
    unsigned short* qb      = Wb + (size_t)3 * D * D;      //  4 MiB
    unsigned short* kb      = qb + (size_t)M * D;          //  4 MiB
    unsigned short* vT      = kb + (size_t)M * D;          //  4 MiB  [B][D][S]

    hipLaunchKernelGGL(cvt_w_kernel, dim3(D * D / 1024, 1, 3), dim3(256), 0, stream,
                       Wq, Wk, Wv, Wb);
    hipLaunchKernelGGL(ln0_kernel, dim3(M), dim3(256), 0, stream, id, g0, b0, id_ln, idln_bf);
    hipLaunchKernelGGL(qkv_mfma_kernel, dim3(D / 128, M / 128, 3), dim3(256), 0, stream,
                       idln_bf, Wb, qb, kb, vT);
    hipLaunchKernelGGL(attn_fused_kernel, dim3(1, S / 64, H * B), dim3(256), 0, stream,
                       qb, kb, vT, Aout, O);
    hipLaunchKernelGGL(final_kernel, dim3(M), dim3(256), 0, stream,
                       id, id_ln, O, g1, b1, g2, b2, out);
}